// Round 12
// baseline (334.838 us; speedup 1.0000x reference)
//
#include <hip/hip_runtime.h>
#include <hip/hip_bf16.h>
#include <math.h>

// Problem dims (fixed by reference)
#define BN 1536          // B*N = 2*768
#define NN 768
#define SCALE 0.17677669529663687f  // 1/sqrt(32)
#define NROWS (BN * NN)  // total edge rows = 1179648

// k_bias geometry
#define BIAS_BLOCKS 2048
#define BIAS_WAVES  (BIAS_BLOCKS * 4)            // 8192
#define BIAS_RPW    (NROWS / BIAS_WAVES)         // 144 rows per wave
#define BIAS_NT     (BIAS_RPW / 4)               // 36 quads (multiple of 3)

// ---- DPP reduction helpers (VALU pipe; no LDS traffic) ---------------------
__device__ __forceinline__ float dpp_add16(float x) {
    int t;
    t = __builtin_amdgcn_update_dpp(0, __float_as_int(x), 0x128, 0xF, 0xF, true); // row_ror:8
    x += __int_as_float(t);
    t = __builtin_amdgcn_update_dpp(0, __float_as_int(x), 0x124, 0xF, 0xF, true); // row_ror:4
    x += __int_as_float(t);
    t = __builtin_amdgcn_update_dpp(0, __float_as_int(x), 0x122, 0xF, 0xF, true); // row_ror:2
    x += __int_as_float(t);
    t = __builtin_amdgcn_update_dpp(0, __float_as_int(x), 0x121, 0xF, 0xF, true); // row_ror:1
    x += __int_as_float(t);
    return x;
}
// 8-lane-group sum, pure DPP (HW-verified via k_attn6 in R8/R9):
// quad_perm xor1 (0xB1), quad_perm xor2 (0x4E), row_half_mirror (0x141).
__device__ __forceinline__ float dpp_add8(float x) {
    int t;
    t = __builtin_amdgcn_update_dpp(0, __float_as_int(x), 0xB1, 0xF, 0xF, true);
    x += __int_as_float(t);
    t = __builtin_amdgcn_update_dpp(0, __float_as_int(x), 0x4E, 0xF, 0xF, true);
    x += __int_as_float(t);
    t = __builtin_amdgcn_update_dpp(0, __float_as_int(x), 0x141, 0xF, 0xF, true);
    x += __int_as_float(t);
    return x;
}

// ---------------------------------------------------------------------------
// K1: x = LN(node); q = SCALE*(x@Wq); k = x@Wk; v = x@Wv; g = sigmoid(x@Wg+bg)
// ---------------------------------------------------------------------------
__global__ __launch_bounds__(256) void k_lnproj(
    const float* __restrict__ node, const float* __restrict__ lnw,
    const float* __restrict__ lnb, const float* __restrict__ Wq,
    const float* __restrict__ Wk, const float* __restrict__ Wv,
    const float* __restrict__ Wg, const float* __restrict__ bg,
    float* __restrict__ q, float* __restrict__ k,
    float* __restrict__ v, float* __restrict__ g)
{
    __shared__ float xs[8][256];
    const int tid = threadIdx.x;
    const int wave = tid >> 6, lane = tid & 63;
    const int row0 = blockIdx.x * 8;

#pragma unroll
    for (int rr = 0; rr < 2; ++rr) {
        const int r = wave * 2 + rr;
        float4 xv = ((const float4*)node)[(size_t)(row0 + r) * 64 + lane];
        float s1 = xv.x + xv.y + xv.z + xv.w;
        float s2 = fmaf(xv.x, xv.x, fmaf(xv.y, xv.y, fmaf(xv.z, xv.z, xv.w * xv.w)));
#pragma unroll
        for (int off = 32; off > 0; off >>= 1) {
            s1 += __shfl_xor(s1, off);
            s2 += __shfl_xor(s2, off);
        }
        const float mu = s1 * (1.f / 256.f);
        const float rstd = rsqrtf(s2 * (1.f / 256.f) - mu * mu + 1e-5f);
        float4 w4 = ((const float4*)lnw)[lane];
        float4 b4 = ((const float4*)lnb)[lane];
        xs[r][lane * 4 + 0] = (xv.x - mu) * rstd * w4.x + b4.x;
        xs[r][lane * 4 + 1] = (xv.y - mu) * rstd * w4.y + b4.y;
        xs[r][lane * 4 + 2] = (xv.z - mu) * rstd * w4.z + b4.z;
        xs[r][lane * 4 + 3] = (xv.w - mu) * rstd * w4.w + b4.w;
    }
    __syncthreads();

    float aq[8] = {}, ak[8] = {}, av[8] = {}, ag[8] = {};
    for (int e4 = 0; e4 < 64; ++e4) {
        const int e = e4 * 4;
        float wq_[4], wk_[4], wv_[4], wg_[4];
#pragma unroll
        for (int t = 0; t < 4; ++t) {
            wq_[t] = Wq[(e + t) * 256 + tid];
            wk_[t] = Wk[(e + t) * 256 + tid];
            wv_[t] = Wv[(e + t) * 256 + tid];
            wg_[t] = Wg[(e + t) * 256 + tid];
        }
#pragma unroll
        for (int r = 0; r < 8; ++r) {
            float4 xr = *(const float4*)&xs[r][e];
            aq[r] = fmaf(xr.x, wq_[0], fmaf(xr.y, wq_[1], fmaf(xr.z, wq_[2], fmaf(xr.w, wq_[3], aq[r]))));
            ak[r] = fmaf(xr.x, wk_[0], fmaf(xr.y, wk_[1], fmaf(xr.z, wk_[2], fmaf(xr.w, wk_[3], ak[r]))));
            av[r] = fmaf(xr.x, wv_[0], fmaf(xr.y, wv_[1], fmaf(xr.z, wv_[2], fmaf(xr.w, wv_[3], av[r]))));
            ag[r] = fmaf(xr.x, wg_[0], fmaf(xr.y, wg_[1], fmaf(xr.z, wg_[2], fmaf(xr.w, wg_[3], ag[r]))));
        }
    }
    const float bgv = bg[tid];
#pragma unroll
    for (int r = 0; r < 8; ++r) {
        const size_t o = (size_t)(row0 + r) * 256 + tid;
        q[o] = aq[r] * SCALE;
        k[o] = ak[r];
        v[o] = av[r];
        g[o] = 1.f / (1.f + __expf(-(ag[r] + bgv)));
    }
}

// ---------------------------------------------------------------------------
// K2a v6 (R9 code — measured ~96us/rep, at the edge-read HBM roofline).
// Zero-LDS, DPP-reduce, all arrays constant-indexed (no address-taking ->
// no PromoteAlloca-to-LDS; that was R2..R8's hidden 16KB LDS + 14M conflicts).
// ---------------------------------------------------------------------------
#define BIAS_BODY(CUR0, CUR1, ITROW)                                          \
    {                                                                         \
        float s1 = ((CUR0.x + CUR0.y) + (CUR0.z + CUR0.w)) +                  \
                   ((CUR1.x + CUR1.y) + (CUR1.z + CUR1.w));                   \
        float s2 = fmaf(CUR0.x, CUR0.x, fmaf(CUR0.y, CUR0.y,                  \
                   fmaf(CUR0.z, CUR0.z, CUR0.w * CUR0.w)));                   \
        s2 = fmaf(CUR1.x, CUR1.x, fmaf(CUR1.y, CUR1.y,                        \
             fmaf(CUR1.z, CUR1.z, fmaf(CUR1.w, CUR1.w, s2))));                \
        float d[8];                                                           \
        _Pragma("unroll")                                                     \
        for (int hh = 0; hh < 8; ++hh) {                                      \
            float a = CUR0.x * wbf[0][hh];                                    \
            a = fmaf(CUR0.y, wbf[1][hh], a);                                  \
            a = fmaf(CUR0.z, wbf[2][hh], a);                                  \
            a = fmaf(CUR0.w, wbf[3][hh], a);                                  \
            a = fmaf(CUR1.x, wbf[4][hh], a);                                  \
            a = fmaf(CUR1.y, wbf[5][hh], a);                                  \
            a = fmaf(CUR1.z, wbf[6][hh], a);                                  \
            a = fmaf(CUR1.w, wbf[7][hh], a);                                  \
            d[hh] = a;                                                        \
        }                                                                     \
        s1 = dpp_add16(s1);                                                   \
        s2 = dpp_add16(s2);                                                   \
        _Pragma("unroll")                                                     \
        for (int hh = 0; hh < 8; ++hh) d[hh] = dpp_add16(d[hh]);              \
        const float mu = s1 * (1.f / 128.f);                                  \
        const float rstd = rsqrtf(s2 * (1.f / 128.f) - mu * mu + 1e-5f);      \
        float dh = d[0];                                                      \
        _Pragma("unroll")                                                     \
        for (int t = 1; t < 8; ++t) dh = (gl == t) ? d[t] : dh;               \
        if (gl < 8)                                                           \
            bias[(size_t)(row0 + (ITROW)) * 8 + gl] =                         \
                rstd * (dh - mu * c1l) + c0l;                                 \
    }

__global__ __launch_bounds__(256, 3) void k_bias(
    const float* __restrict__ edge, const float* __restrict__ lnw,
    const float* __restrict__ lnb, const float* __restrict__ Wb,
    float* __restrict__ bias, int reps)
{
    const int tid = threadIdx.x;
    const int wv = tid >> 6, lane = tid & 63;
    const int gl = lane & 15;
    const int rg = lane >> 4;

    float wbf[8][8];
    float c1a[8], c0a[8];
#pragma unroll
    for (int hh = 0; hh < 8; ++hh) { c1a[hh] = 0.f; c0a[hh] = 0.f; }
#pragma unroll
    for (int t = 0; t < 8; ++t) {
        const int c = (t < 4) ? (gl * 4 + t) : (64 + gl * 4 + (t - 4));
        const float w = lnw[c], bb = lnb[c];
        const float4 wa = ((const float4*)Wb)[c * 2];
        const float4 wc = ((const float4*)Wb)[c * 2 + 1];
        wbf[t][0] = w * wa.x; wbf[t][1] = w * wa.y;
        wbf[t][2] = w * wa.z; wbf[t][3] = w * wa.w;
        wbf[t][4] = w * wc.x; wbf[t][5] = w * wc.y;
        wbf[t][6] = w * wc.z; wbf[t][7] = w * wc.w;
        c0a[0] = fmaf(bb, wa.x, c0a[0]); c0a[1] = fmaf(bb, wa.y, c0a[1]);
        c0a[2] = fmaf(bb, wa.z, c0a[2]); c0a[3] = fmaf(bb, wa.w, c0a[3]);
        c0a[4] = fmaf(bb, wc.x, c0a[4]); c0a[5] = fmaf(bb, wc.y, c0a[5]);
        c0a[6] = fmaf(bb, wc.z, c0a[6]); c0a[7] = fmaf(bb, wc.w, c0a[7]);
#pragma unroll
        for (int hh = 0; hh < 8; ++hh) c1a[hh] += wbf[t][hh];
    }
#pragma unroll
    for (int hh = 0; hh < 8; ++hh) {
        c1a[hh] = dpp_add16(c1a[hh]);
        c0a[hh] = dpp_add16(c0a[hh]);
    }
    float c1l = c1a[0], c0l = c0a[0];
#pragma unroll
    for (int t = 1; t < 8; ++t) {
        const bool e = ((gl & 7) == t);
        c1l = e ? c1a[t] : c1l;
        c0l = e ? c0a[t] : c0l;
    }

    const int w = blockIdx.x * 4 + wv;     // 0..8191
    const int row0 = w * BIAS_RPW;         // 144 rows/wave
    const float4* ep = (const float4*)edge;

    for (int rep = 0; rep < reps; ++rep) {
        float4 A0, A1, B0, B1, C0, C1;
        {
            const size_t r = (size_t)(row0 + rg);
            A0 = ep[r * 32 + gl]; A1 = ep[r * 32 + 16 + gl];
        }
        {
            const size_t r = (size_t)(row0 + 4 + rg);
            B0 = ep[r * 32 + gl]; B1 = ep[r * 32 + 16 + gl];
        }

#define BSTEP(IT, CUR0, CUR1, NXT0, NXT1)                                 \
        {                                                                 \
            if ((IT) + 2 < BIAS_NT) {                                     \
                const size_t r = (size_t)(row0 + ((IT) + 2) * 4 + rg);    \
                NXT0 = ep[r * 32 + gl]; NXT1 = ep[r * 32 + 16 + gl];      \
            }                                                             \
            BIAS_BODY(CUR0, CUR1, (IT) * 4 + rg);                         \
        }

        for (int it = 0; it < BIAS_NT; it += 3) {
            BSTEP(it,     A0, A1, C0, C1);
            BSTEP(it + 1, B0, B1, A0, A1);
            BSTEP(it + 2, C0, C1, B0, B1);
        }
#undef BSTEP
    }
}

// ---------------------------------------------------------------------------
// K2b v6 (R9 code — measured 105us/rep, VALUBusy 57.7%, Occ 67.8%).
// One block per (b,i), 4 waves x 192 j's; coalesced K/V row reads (all 64
// lanes on one contiguous 1KB row); pure-DPP octet reduce; LDS merge at end.
// R10/R11 lesson: in this 90%-stall latency regime TLP wins — do NOT trade
// wave count for per-wave ILP (attn8: 2 rows/wave, half the waves -> 2x slower)
// and do NOT trade coalescing for lane-local dots (attn7: 3x slower).
// ---------------------------------------------------------------------------
__global__ __launch_bounds__(256, 4) void k_attn6(
    const float* __restrict__ bias,
    const float* __restrict__ q, const float* __restrict__ k,
    const float* __restrict__ v, const float* __restrict__ g,
    float* __restrict__ res, int reps)
{
    __shared__ float mg[4][64][6];
    const int tid = threadIdx.x;
    const int wv = tid >> 6, lane = tid & 63;
    const int bi = blockIdx.x;
    const int b = bi / NN;
    const int h = lane >> 3;

    const float4 q4 = ((const float4*)q)[(size_t)bi * 64 + lane];
    const float* brow = bias + (size_t)bi * NN * 8;
    const size_t kb = (size_t)b * NN * 64;
    const int j0 = wv * (NN / 4);     // 0,192,384,576

    for (int rep = 0; rep < reps; ++rep) {
        float m = -3e38f, s = 0.f;
        float4 acc = make_float4(0.f, 0.f, 0.f, 0.f);

        for (int t = 0; t < NN / 16; ++t) {      // 48 iters x 4 j
            const int jb = j0 + t * 4;
            float l[4];
            float4 vc[4];
#pragma unroll
            for (int u = 0; u < 4; ++u) {
                const float4 kc = ((const float4*)k)[kb + (size_t)(jb + u) * 64 + lane];
                vc[u] = ((const float4*)v)[kb + (size_t)(jb + u) * 64 + lane];
                float d = fmaf(q4.x, kc.x, fmaf(q4.y, kc.y,
                          fmaf(q4.z, kc.z, q4.w * kc.w)));
                d = dpp_add8(d);
                l[u] = d + brow[(jb + u) * 8 + h];
            }
            const float lm = fmaxf(fmaxf(l[0], l[1]), fmaxf(l[2], l[3]));
            const float mn = fmaxf(m, lm);
            const float sc = __expf(m - mn);
            float p[4];
#pragma unroll
            for (int u = 0; u < 4; ++u) p[u] = __expf(l[u] - mn);
            s = fmaf(s, sc, (p[0] + p[1]) + (p[2] + p[3]));
            m = mn;
            acc.x = fmaf(p[3], vc[3].x, fmaf(p[2], vc[2].x,
                    fmaf(p[1], vc[1].x, fmaf(p[0], vc[0].x, acc.x * sc))));
            acc.y = fmaf(p[3], vc[3].y, fmaf(p[2], vc[2].y,
                    fmaf(p[1], vc[1].y, fmaf(p[0], vc[0].y, acc.y * sc))));
            acc.z = fmaf(p[3], vc[3].z, fmaf(p[2], vc[2].z,
                    fmaf(p[1], vc[1].z, fmaf(p[0], vc[0].z, acc.z * sc))));
            acc.w = fmaf(p[3], vc[3].w, fmaf(p[2], vc[2].w,
                    fmaf(p[1], vc[1].w, fmaf(p[0], vc[0].w, acc.w * sc))));
        }

        mg[wv][lane][0] = m;
        mg[wv][lane][1] = s;
        mg[wv][lane][2] = acc.x;
        mg[wv][lane][3] = acc.y;
        mg[wv][lane][4] = acc.z;
        mg[wv][lane][5] = acc.w;
        __syncthreads();
        if (wv == 0) {
            float M = mg[0][lane][0];
#pragma unroll
            for (int w2 = 1; w2 < 4; ++w2) M = fmaxf(M, mg[w2][lane][0]);
            float S = 0.f;
            float4 A = make_float4(0.f, 0.f, 0.f, 0.f);
#pragma unroll
            for (int w2 = 0; w2 < 4; ++w2) {
                const float sc2 = __expf(mg[w2][lane][0] - M);
                S = fmaf(mg[w2][lane][1], sc2, S);
                A.x = fmaf(mg[w2][lane][2], sc2, A.x);
                A.y = fmaf(mg[w2][lane][3], sc2, A.y);
                A.z = fmaf(mg[w2][lane][4], sc2, A.z);
                A.w = fmaf(mg[w2][lane][5], sc2, A.w);
            }
            const float4 g4 = ((const float4*)g)[(size_t)bi * 64 + lane];
            const float inv = 1.f / S;
            float4 r;
            r.x = A.x * inv * g4.x;
            r.y = A.y * inv * g4.y;
            r.z = A.z * inv * g4.z;
            r.w = A.w * inv * g4.w;
            ((float4*)res)[(size_t)bi * 64 + lane] = r;
        }
        __syncthreads();
    }
}

// ---------------------------------------------------------------------------
// K3: out = res @ Wo + bo.  8 rows per block.
// ---------------------------------------------------------------------------
__global__ __launch_bounds__(256) void k_outproj(
    const float* __restrict__ res, const float* __restrict__ Wo,
    const float* __restrict__ bo, float* __restrict__ out)
{
    __shared__ float xs[8][256];
    const int tid = threadIdx.x;
    const int row0 = blockIdx.x * 8;

#pragma unroll
    for (int t = tid; t < 512; t += 256)
        ((float4*)&xs[0][0])[t] = ((const float4*)(res + (size_t)row0 * 256))[t];
    __syncthreads();

    float a[8] = {};
    for (int e4 = 0; e4 < 64; ++e4) {
        const int e = e4 * 4;
        float w_[4];
#pragma unroll
        for (int t = 0; t < 4; ++t) w_[t] = Wo[(e + t) * 256 + tid];
#pragma unroll
        for (int r = 0; r < 8; ++r) {
            float4 xr = *(const float4*)&xs[r][e];
            a[r] = fmaf(xr.x, w_[0], fmaf(xr.y, w_[1], fmaf(xr.z, w_[2], fmaf(xr.w, w_[3], a[r]))));
        }
    }
    const float bov = bo[tid];
#pragma unroll
    for (int r = 0; r < 8; ++r)
        out[(size_t)(row0 + r) * 256 + tid] = a[r] + bov;
}

// ---------------------------------------------------------------------------
extern "C" void kernel_launch(void* const* d_in, const int* in_sizes, int n_in,
                              void* d_out, int out_size, void* d_ws, size_t ws_size,
                              hipStream_t stream) {
    const float* node = (const float*)d_in[0];
    const float* edge = (const float*)d_in[1];
    const float* lnnw = (const float*)d_in[2];
    const float* lnnb = (const float*)d_in[3];
    const float* lnew = (const float*)d_in[4];
    const float* lneb = (const float*)d_in[5];
    const float* Wq   = (const float*)d_in[6];
    const float* Wk   = (const float*)d_in[7];
    const float* Wv   = (const float*)d_in[8];
    const float* Wb   = (const float*)d_in[9];
    const float* Wg   = (const float*)d_in[10];
    const float* bg   = (const float*)d_in[11];
    const float* Wo   = (const float*)d_in[12];
    const float* bo   = (const float*)d_in[13];
    float* out = (float*)d_out;

    float* ws = (float*)d_ws;
    const size_t NT = (size_t)BN * 256;
    float* q    = ws;
    float* k    = ws + NT;
    float* v    = ws + 2 * NT;
    float* g    = ws + 3 * NT;
    float* res  = ws + 4 * NT;
    float* bias = ws + 5 * NT;            // 9.44M floats = 37.75 MB

    k_lnproj<<<BN / 8, 256, 0, stream>>>(node, lnnw, lnnb, Wq, Wk, Wv, Wg, bg, q, k, v, g);
    k_bias<<<BIAS_BLOCKS, 256, 0, stream>>>(edge, lnew, lneb, Wb, bias, 1);
    k_attn6<<<BN, 256, 0, stream>>>(bias, q, k, v, g, res, 1);
    k_outproj<<<BN / 8, 256, 0, stream>>>(res, Wo, bo, out);
}

// Round 13
// 329.373 us; speedup vs baseline: 1.0166x; 1.0166x over previous
//
#include <hip/hip_runtime.h>
#include <hip/hip_bf16.h>
#include <math.h>

// Problem dims (fixed by reference)
#define BN 1536          // B*N = 2*768
#define NN 768
#define SCALE 0.17677669529663687f  // 1/sqrt(32)
#define NROWS (BN * NN)  // total edge rows = 1179648

// k_bias geometry
#define BIAS_BLOCKS 2048
#define BIAS_WAVES  (BIAS_BLOCKS * 4)            // 8192
#define BIAS_RPW    (NROWS / BIAS_WAVES)         // 144 rows per wave
#define BIAS_NT     (BIAS_RPW / 4)               // 36 quads (multiple of 3)

// ---- DPP reduction helpers (VALU pipe; no LDS traffic) ---------------------
__device__ __forceinline__ float dpp_add16(float x) {
    int t;
    t = __builtin_amdgcn_update_dpp(0, __float_as_int(x), 0x128, 0xF, 0xF, true); // row_ror:8
    x += __int_as_float(t);
    t = __builtin_amdgcn_update_dpp(0, __float_as_int(x), 0x124, 0xF, 0xF, true); // row_ror:4
    x += __int_as_float(t);
    t = __builtin_amdgcn_update_dpp(0, __float_as_int(x), 0x122, 0xF, 0xF, true); // row_ror:2
    x += __int_as_float(t);
    t = __builtin_amdgcn_update_dpp(0, __float_as_int(x), 0x121, 0xF, 0xF, true); // row_ror:1
    x += __int_as_float(t);
    return x;
}
// 8-lane-group sum, pure DPP (HW-verified via k_attn6 in R8/R9):
// quad_perm xor1 (0xB1), quad_perm xor2 (0x4E), row_half_mirror (0x141).
__device__ __forceinline__ float dpp_add8(float x) {
    int t;
    t = __builtin_amdgcn_update_dpp(0, __float_as_int(x), 0xB1, 0xF, 0xF, true);
    x += __int_as_float(t);
    t = __builtin_amdgcn_update_dpp(0, __float_as_int(x), 0x4E, 0xF, 0xF, true);
    x += __int_as_float(t);
    t = __builtin_amdgcn_update_dpp(0, __float_as_int(x), 0x141, 0xF, 0xF, true);
    x += __int_as_float(t);
    return x;
}

// ---------------------------------------------------------------------------
// K1: x = LN(node); q = SCALE*(x@Wq); k = x@Wk; v = x@Wv; g = sigmoid(x@Wg+bg)
// ---------------------------------------------------------------------------
__global__ __launch_bounds__(256) void k_lnproj(
    const float* __restrict__ node, const float* __restrict__ lnw,
    const float* __restrict__ lnb, const float* __restrict__ Wq,
    const float* __restrict__ Wk, const float* __restrict__ Wv,
    const float* __restrict__ Wg, const float* __restrict__ bg,
    float* __restrict__ q, float* __restrict__ k,
    float* __restrict__ v, float* __restrict__ g)
{
    __shared__ float xs[8][256];
    const int tid = threadIdx.x;
    const int wave = tid >> 6, lane = tid & 63;
    const int row0 = blockIdx.x * 8;

#pragma unroll
    for (int rr = 0; rr < 2; ++rr) {
        const int r = wave * 2 + rr;
        float4 xv = ((const float4*)node)[(size_t)(row0 + r) * 64 + lane];
        float s1 = xv.x + xv.y + xv.z + xv.w;
        float s2 = fmaf(xv.x, xv.x, fmaf(xv.y, xv.y, fmaf(xv.z, xv.z, xv.w * xv.w)));
#pragma unroll
        for (int off = 32; off > 0; off >>= 1) {
            s1 += __shfl_xor(s1, off);
            s2 += __shfl_xor(s2, off);
        }
        const float mu = s1 * (1.f / 256.f);
        const float rstd = rsqrtf(s2 * (1.f / 256.f) - mu * mu + 1e-5f);
        float4 w4 = ((const float4*)lnw)[lane];
        float4 b4 = ((const float4*)lnb)[lane];
        xs[r][lane * 4 + 0] = (xv.x - mu) * rstd * w4.x + b4.x;
        xs[r][lane * 4 + 1] = (xv.y - mu) * rstd * w4.y + b4.y;
        xs[r][lane * 4 + 2] = (xv.z - mu) * rstd * w4.z + b4.z;
        xs[r][lane * 4 + 3] = (xv.w - mu) * rstd * w4.w + b4.w;
    }
    __syncthreads();

    float aq[8] = {}, ak[8] = {}, av[8] = {}, ag[8] = {};
    for (int e4 = 0; e4 < 64; ++e4) {
        const int e = e4 * 4;
        float wq_[4], wk_[4], wv_[4], wg_[4];
#pragma unroll
        for (int t = 0; t < 4; ++t) {
            wq_[t] = Wq[(e + t) * 256 + tid];
            wk_[t] = Wk[(e + t) * 256 + tid];
            wv_[t] = Wv[(e + t) * 256 + tid];
            wg_[t] = Wg[(e + t) * 256 + tid];
        }
#pragma unroll
        for (int r = 0; r < 8; ++r) {
            float4 xr = *(const float4*)&xs[r][e];
            aq[r] = fmaf(xr.x, wq_[0], fmaf(xr.y, wq_[1], fmaf(xr.z, wq_[2], fmaf(xr.w, wq_[3], aq[r]))));
            ak[r] = fmaf(xr.x, wk_[0], fmaf(xr.y, wk_[1], fmaf(xr.z, wk_[2], fmaf(xr.w, wk_[3], ak[r]))));
            av[r] = fmaf(xr.x, wv_[0], fmaf(xr.y, wv_[1], fmaf(xr.z, wv_[2], fmaf(xr.w, wv_[3], av[r]))));
            ag[r] = fmaf(xr.x, wg_[0], fmaf(xr.y, wg_[1], fmaf(xr.z, wg_[2], fmaf(xr.w, wg_[3], ag[r]))));
        }
    }
    const float bgv = bg[tid];
#pragma unroll
    for (int r = 0; r < 8; ++r) {
        const size_t o = (size_t)(row0 + r) * 256 + tid;
        q[o] = aq[r] * SCALE;
        k[o] = ak[r];
        v[o] = av[r];
        g[o] = 1.f / (1.f + __expf(-(ag[r] + bgv)));
    }
}

// ---------------------------------------------------------------------------
// K2a v6 (R9 code — measured ~94us/rep, at the edge-read HBM roofline).
// Zero-LDS, DPP-reduce, all arrays constant-indexed (no address-taking ->
// no PromoteAlloca-to-LDS; that was R2..R8's hidden 16KB LDS + 14M conflicts).
// ---------------------------------------------------------------------------
#define BIAS_BODY(CUR0, CUR1, ITROW)                                          \
    {                                                                         \
        float s1 = ((CUR0.x + CUR0.y) + (CUR0.z + CUR0.w)) +                  \
                   ((CUR1.x + CUR1.y) + (CUR1.z + CUR1.w));                   \
        float s2 = fmaf(CUR0.x, CUR0.x, fmaf(CUR0.y, CUR0.y,                  \
                   fmaf(CUR0.z, CUR0.z, CUR0.w * CUR0.w)));                   \
        s2 = fmaf(CUR1.x, CUR1.x, fmaf(CUR1.y, CUR1.y,                        \
             fmaf(CUR1.z, CUR1.z, fmaf(CUR1.w, CUR1.w, s2))));                \
        float d[8];                                                           \
        _Pragma("unroll")                                                     \
        for (int hh = 0; hh < 8; ++hh) {                                      \
            float a = CUR0.x * wbf[0][hh];                                    \
            a = fmaf(CUR0.y, wbf[1][hh], a);                                  \
            a = fmaf(CUR0.z, wbf[2][hh], a);                                  \
            a = fmaf(CUR0.w, wbf[3][hh], a);                                  \
            a = fmaf(CUR1.x, wbf[4][hh], a);                                  \
            a = fmaf(CUR1.y, wbf[5][hh], a);                                  \
            a = fmaf(CUR1.z, wbf[6][hh], a);                                  \
            a = fmaf(CUR1.w, wbf[7][hh], a);                                  \
            d[hh] = a;                                                        \
        }                                                                     \
        s1 = dpp_add16(s1);                                                   \
        s2 = dpp_add16(s2);                                                   \
        _Pragma("unroll")                                                     \
        for (int hh = 0; hh < 8; ++hh) d[hh] = dpp_add16(d[hh]);              \
        const float mu = s1 * (1.f / 128.f);                                  \
        const float rstd = rsqrtf(s2 * (1.f / 128.f) - mu * mu + 1e-5f);      \
        float dh = d[0];                                                      \
        _Pragma("unroll")                                                     \
        for (int t = 1; t < 8; ++t) dh = (gl == t) ? d[t] : dh;               \
        if (gl < 8)                                                           \
            bias[(size_t)(row0 + (ITROW)) * 8 + gl] =                         \
                rstd * (dh - mu * c1l) + c0l;                                 \
    }

__global__ __launch_bounds__(256, 3) void k_bias(
    const float* __restrict__ edge, const float* __restrict__ lnw,
    const float* __restrict__ lnb, const float* __restrict__ Wb,
    float* __restrict__ bias, int reps)
{
    const int tid = threadIdx.x;
    const int wv = tid >> 6, lane = tid & 63;
    const int gl = lane & 15;
    const int rg = lane >> 4;

    float wbf[8][8];
    float c1a[8], c0a[8];
#pragma unroll
    for (int hh = 0; hh < 8; ++hh) { c1a[hh] = 0.f; c0a[hh] = 0.f; }
#pragma unroll
    for (int t = 0; t < 8; ++t) {
        const int c = (t < 4) ? (gl * 4 + t) : (64 + gl * 4 + (t - 4));
        const float w = lnw[c], bb = lnb[c];
        const float4 wa = ((const float4*)Wb)[c * 2];
        const float4 wc = ((const float4*)Wb)[c * 2 + 1];
        wbf[t][0] = w * wa.x; wbf[t][1] = w * wa.y;
        wbf[t][2] = w * wa.z; wbf[t][3] = w * wa.w;
        wbf[t][4] = w * wc.x; wbf[t][5] = w * wc.y;
        wbf[t][6] = w * wc.z; wbf[t][7] = w * wc.w;
        c0a[0] = fmaf(bb, wa.x, c0a[0]); c0a[1] = fmaf(bb, wa.y, c0a[1]);
        c0a[2] = fmaf(bb, wa.z, c0a[2]); c0a[3] = fmaf(bb, wa.w, c0a[3]);
        c0a[4] = fmaf(bb, wc.x, c0a[4]); c0a[5] = fmaf(bb, wc.y, c0a[5]);
        c0a[6] = fmaf(bb, wc.z, c0a[6]); c0a[7] = fmaf(bb, wc.w, c0a[7]);
#pragma unroll
        for (int hh = 0; hh < 8; ++hh) c1a[hh] += wbf[t][hh];
    }
#pragma unroll
    for (int hh = 0; hh < 8; ++hh) {
        c1a[hh] = dpp_add16(c1a[hh]);
        c0a[hh] = dpp_add16(c0a[hh]);
    }
    float c1l = c1a[0], c0l = c0a[0];
#pragma unroll
    for (int t = 1; t < 8; ++t) {
        const bool e = ((gl & 7) == t);
        c1l = e ? c1a[t] : c1l;
        c0l = e ? c0a[t] : c0l;
    }

    const int w = blockIdx.x * 4 + wv;     // 0..8191
    const int row0 = w * BIAS_RPW;         // 144 rows/wave
    const float4* ep = (const float4*)edge;

    for (int rep = 0; rep < reps; ++rep) {
        float4 A0, A1, B0, B1, C0, C1;
        {
            const size_t r = (size_t)(row0 + rg);
            A0 = ep[r * 32 + gl]; A1 = ep[r * 32 + 16 + gl];
        }
        {
            const size_t r = (size_t)(row0 + 4 + rg);
            B0 = ep[r * 32 + gl]; B1 = ep[r * 32 + 16 + gl];
        }

#define BSTEP(IT, CUR0, CUR1, NXT0, NXT1)                                 \
        {                                                                 \
            if ((IT) + 2 < BIAS_NT) {                                     \
                const size_t r = (size_t)(row0 + ((IT) + 2) * 4 + rg);    \
                NXT0 = ep[r * 32 + gl]; NXT1 = ep[r * 32 + 16 + gl];      \
            }                                                             \
            BIAS_BODY(CUR0, CUR1, (IT) * 4 + rg);                         \
        }

        for (int it = 0; it < BIAS_NT; it += 3) {
            BSTEP(it,     A0, A1, C0, C1);
            BSTEP(it + 1, B0, B1, A0, A1);
            BSTEP(it + 2, C0, C1, B0, B1);
        }
#undef BSTEP
    }
}

// ---------------------------------------------------------------------------
// K2b v9: attn6 body, j-range split across 2 blocks per (b,i) row to lift
// occupancy past the grid cap (R9: 67.8% occ = 24/32 waves, grid-limited).
// grid 3072 = 12 blocks/CU -> 48 waves demanded -> occupancy pins at 100%.
// Block (bi = blk>>1, jh = blk&1): 4 waves x 96 j's each (24 iters x 4 j).
// Coalesced K/V row reads + pure-DPP octet reduce (R10/R11 lessons: keep
// coalescing, maximize TLP). Per-block partial (m,s,acc) -> ws; k_amerge
// folds the two halves + gate into res.
// ---------------------------------------------------------------------------
__global__ __launch_bounds__(256, 4) void k_attn9(
    const float* __restrict__ bias,
    const float* __restrict__ q, const float* __restrict__ k,
    const float* __restrict__ v,
    float2* __restrict__ pms, float4* __restrict__ pacc)
{
    __shared__ float mg[4][64][6];
    const int tid = threadIdx.x;
    const int wv = tid >> 6, lane = tid & 63;
    const int blk = blockIdx.x;
    const int bi = blk >> 1, jh = blk & 1;
    const int b = bi / NN;
    const int h = lane >> 3;

    const float4 q4 = ((const float4*)q)[(size_t)bi * 64 + lane];
    const float* brow = bias + (size_t)bi * NN * 8;
    const size_t kb = (size_t)b * NN * 64;
    const int j0 = jh * (NN / 2) + wv * (NN / 8);   // wave's 96-j window

    float m = -3e38f, s = 0.f;
    float4 acc = make_float4(0.f, 0.f, 0.f, 0.f);

    for (int t = 0; t < NN / 32; ++t) {      // 24 iters x 4 j
        const int jb = j0 + t * 4;
        float l[4];
        float4 vc[4];
#pragma unroll
        for (int u = 0; u < 4; ++u) {
            const float4 kc = ((const float4*)k)[kb + (size_t)(jb + u) * 64 + lane];
            vc[u] = ((const float4*)v)[kb + (size_t)(jb + u) * 64 + lane];
            float d = fmaf(q4.x, kc.x, fmaf(q4.y, kc.y,
                      fmaf(q4.z, kc.z, q4.w * kc.w)));
            d = dpp_add8(d);
            l[u] = d + brow[(jb + u) * 8 + h];
        }
        const float lm = fmaxf(fmaxf(l[0], l[1]), fmaxf(l[2], l[3]));
        const float mn = fmaxf(m, lm);
        const float sc = __expf(m - mn);
        float p[4];
#pragma unroll
        for (int u = 0; u < 4; ++u) p[u] = __expf(l[u] - mn);
        s = fmaf(s, sc, (p[0] + p[1]) + (p[2] + p[3]));
        m = mn;
        acc.x = fmaf(p[3], vc[3].x, fmaf(p[2], vc[2].x,
                fmaf(p[1], vc[1].x, fmaf(p[0], vc[0].x, acc.x * sc))));
        acc.y = fmaf(p[3], vc[3].y, fmaf(p[2], vc[2].y,
                fmaf(p[1], vc[1].y, fmaf(p[0], vc[0].y, acc.y * sc))));
        acc.z = fmaf(p[3], vc[3].z, fmaf(p[2], vc[2].z,
                fmaf(p[1], vc[1].z, fmaf(p[0], vc[0].z, acc.z * sc))));
        acc.w = fmaf(p[3], vc[3].w, fmaf(p[2], vc[2].w,
                fmaf(p[1], vc[1].w, fmaf(p[0], vc[0].w, acc.w * sc))));
    }

    mg[wv][lane][0] = m;
    mg[wv][lane][1] = s;
    mg[wv][lane][2] = acc.x;
    mg[wv][lane][3] = acc.y;
    mg[wv][lane][4] = acc.z;
    mg[wv][lane][5] = acc.w;
    __syncthreads();
    if (wv == 0) {
        float M = mg[0][lane][0];
#pragma unroll
        for (int w2 = 1; w2 < 4; ++w2) M = fmaxf(M, mg[w2][lane][0]);
        float S = 0.f;
        float4 A = make_float4(0.f, 0.f, 0.f, 0.f);
#pragma unroll
        for (int w2 = 0; w2 < 4; ++w2) {
            const float sc2 = __expf(mg[w2][lane][0] - M);
            S = fmaf(mg[w2][lane][1], sc2, S);
            A.x = fmaf(mg[w2][lane][2], sc2, A.x);
            A.y = fmaf(mg[w2][lane][3], sc2, A.y);
            A.z = fmaf(mg[w2][lane][4], sc2, A.z);
            A.w = fmaf(mg[w2][lane][5], sc2, A.w);
        }
        pms[(size_t)blk * 64 + lane] = make_float2(M, S);
        pacc[(size_t)blk * 64 + lane] = A;
    }
}

// ---------------------------------------------------------------------------
// K2c: merge the two j-half partials per row, apply gate, write res.
// 384 blocks x 256 threads; thread -> (bi = gid>>6, lane = gid&63). Coalesced.
// ---------------------------------------------------------------------------
__global__ __launch_bounds__(256) void k_amerge(
    const float2* __restrict__ pms, const float4* __restrict__ pacc,
    const float* __restrict__ g, float* __restrict__ res)
{
    const int gid = blockIdx.x * 256 + threadIdx.x;   // 0..98303
    const int bi = gid >> 6, l = gid & 63;
    const size_t i0 = (size_t)(bi * 2 + 0) * 64 + l;
    const size_t i1 = (size_t)(bi * 2 + 1) * 64 + l;
    const float2 ms0 = pms[i0];
    const float2 ms1 = pms[i1];
    const float4 a0 = pacc[i0];
    const float4 a1 = pacc[i1];
    const float M = fmaxf(ms0.x, ms1.x);
    const float e0 = __expf(ms0.x - M);
    const float e1 = __expf(ms1.x - M);
    const float S = ms0.y * e0 + ms1.y * e1;
    const float inv = 1.f / S;
    const float4 g4 = ((const float4*)g)[(size_t)bi * 64 + l];
    float4 o;
    o.x = (a0.x * e0 + a1.x * e1) * inv * g4.x;
    o.y = (a0.y * e0 + a1.y * e1) * inv * g4.y;
    o.z = (a0.z * e0 + a1.z * e1) * inv * g4.z;
    o.w = (a0.w * e0 + a1.w * e1) * inv * g4.w;
    ((float4*)res)[(size_t)bi * 64 + l] = o;
}

// ---------------------------------------------------------------------------
// K3: out = res @ Wo + bo.  8 rows per block.
// ---------------------------------------------------------------------------
__global__ __launch_bounds__(256) void k_outproj(
    const float* __restrict__ res, const float* __restrict__ Wo,
    const float* __restrict__ bo, float* __restrict__ out)
{
    __shared__ float xs[8][256];
    const int tid = threadIdx.x;
    const int row0 = blockIdx.x * 8;

#pragma unroll
    for (int t = tid; t < 512; t += 256)
        ((float4*)&xs[0][0])[t] = ((const float4*)(res + (size_t)row0 * 256))[t];
    __syncthreads();

    float a[8] = {};
    for (int e4 = 0; e4 < 64; ++e4) {
        const int e = e4 * 4;
        float w_[4];
#pragma unroll
        for (int t = 0; t < 4; ++t) w_[t] = Wo[(e + t) * 256 + tid];
#pragma unroll
        for (int r = 0; r < 8; ++r) {
            float4 xr = *(const float4*)&xs[r][e];
            a[r] = fmaf(xr.x, w_[0], fmaf(xr.y, w_[1], fmaf(xr.z, w_[2], fmaf(xr.w, w_[3], a[r]))));
        }
    }
    const float bov = bo[tid];
#pragma unroll
    for (int r = 0; r < 8; ++r)
        out[(size_t)(row0 + r) * 256 + tid] = a[r] + bov;
}

// ---------------------------------------------------------------------------
extern "C" void kernel_launch(void* const* d_in, const int* in_sizes, int n_in,
                              void* d_out, int out_size, void* d_ws, size_t ws_size,
                              hipStream_t stream) {
    const float* node = (const float*)d_in[0];
    const float* edge = (const float*)d_in[1];
    const float* lnnw = (const float*)d_in[2];
    const float* lnnb = (const float*)d_in[3];
    const float* lnew = (const float*)d_in[4];
    const float* lneb = (const float*)d_in[5];
    const float* Wq   = (const float*)d_in[6];
    const float* Wk   = (const float*)d_in[7];
    const float* Wv   = (const float*)d_in[8];
    const float* Wb   = (const float*)d_in[9];
    const float* Wg   = (const float*)d_in[10];
    const float* bg   = (const float*)d_in[11];
    const float* Wo   = (const float*)d_in[12];
    const float* bo   = (const float*)d_in[13];
    float* out = (float*)d_out;

    float* ws = (float*)d_ws;
    const size_t NT = (size_t)BN * 256;
    float* q    = ws;
    float* k    = ws + NT;
    float* v    = ws + 2 * NT;
    float* g    = ws + 3 * NT;
    float* res  = ws + 4 * NT;
    float* bias = ws + 5 * NT;                    // 9.44M floats = 37.75 MB
    float* pms  = ws + 5 * NT + (size_t)NROWS * 8;       // 3072*64*2 floats
    float* pacc = pms + (size_t)3072 * 64 * 2;           // 3072*64*4 floats

    k_lnproj<<<BN / 8, 256, 0, stream>>>(node, lnnw, lnnb, Wq, Wk, Wv, Wg, bg, q, k, v, g);
    k_bias<<<BIAS_BLOCKS, 256, 0, stream>>>(edge, lnew, lneb, Wb, bias, 1);
    k_attn9<<<BN * 2, 256, 0, stream>>>(bias, q, k, v, (float2*)pms, (float4*)pacc);
    k_amerge<<<BN * 64 / 256, 256, 0, stream>>>((const float2*)pms, (const float4*)pacc, g, res);
    k_outproj<<<BN / 8, 256, 0, stream>>>(res, Wo, bo, out);
}